// Round 1
// baseline (5885.869 us; speedup 1.0000x reference)
//
#include <hip/hip_runtime.h>
#include <hip/hip_bf16.h>
#include <cstddef>

#define L_SEQ   4096
#define BATCH   32
#define TOFF    1024
#define TBUF    3072
#define NLAYERS 30

static const size_t HSZ = (size_t)BATCH * TBUF * 64;  // 6,291,456 floats per h buffer

// ---------------------------------------------------------------------------
// fast activations (error ~1e-7, threshold is 2.3e-2)
// ---------------------------------------------------------------------------
__device__ inline float fast_sigmoid(float x) {
  x = fminf(fmaxf(x, -30.f), 30.f);
  return __builtin_amdgcn_rcpf(1.f + __expf(-x));
}
__device__ inline float fast_tanh(float x) {
  x = fminf(fmaxf(x, -15.f), 15.f);
  float e = __expf(-2.f * x);
  return (1.f - e) * __builtin_amdgcn_rcpf(1.f + e);
}

// ---------------------------------------------------------------------------
// prep: pack dil/gate taps per output channel, transpose res_w/skip_w,
// zero skip_last accumulator.
// pk layout: [30][oc=64][256]: [0:64)=wd0, [64:128)=wd1, [128:192)=wg0, [192:256)=wg1
// resT/skipT layout: [30][dc=64][oc_out=64] (transposed for outer-product accum)
// ---------------------------------------------------------------------------
__global__ __launch_bounds__(256) void prep_kernel(
    const float* __restrict__ dil_w, const float* __restrict__ gate_w,
    const float* __restrict__ res_w, const float* __restrict__ skip_w,
    float* __restrict__ pk, float* __restrict__ resT, float* __restrict__ skipT,
    float* __restrict__ skip_last)
{
  int idx = blockIdx.x * 256 + threadIdx.x;
  const int total_pk = NLAYERS * 64 * 256;
  if (idx < total_pk) {
    int lo  = idx >> 8;     // layer*64 + oc
    int r   = idx & 255;
    int k   = r & 63;
    int sel = r >> 6;
    float v;
    if      (sel == 0) v = dil_w [(lo * 64 + k) * 2 + 0];
    else if (sel == 1) v = dil_w [(lo * 64 + k) * 2 + 1];
    else if (sel == 2) v = gate_w[(lo * 64 + k) * 2 + 0];
    else               v = gate_w[(lo * 64 + k) * 2 + 1];
    pk[idx] = v;
  }
  const int total_t = NLAYERS * 64 * 64;
  if (idx < total_t) {
    int i  = idx >> 12;     // layer
    int r  = idx & 4095;
    int dc = r >> 6;        // input channel (z index)
    int oc = r & 63;        // output channel
    resT [idx] = res_w [((size_t)i * 64 + oc) * 64 + dc];
    skipT[idx] = skip_w[((size_t)i * 64 + oc) * 64 + dc];
  }
  if (idx < BATCH * 64) skip_last[idx] = 0.f;
}

// ---------------------------------------------------------------------------
// input 1x1 conv: h0[b][t][c] for t in [1027, 4096)
// ---------------------------------------------------------------------------
__global__ __launch_bounds__(256) void input_conv_kernel(
    const float* __restrict__ x, const float* __restrict__ w,
    const float* __restrict__ bias, float* __restrict__ h)
{
  int b = blockIdx.y;
  int t = 1027 + blockIdx.x * 256 + threadIdx.x;
  if (t >= L_SEQ) return;
  const float* xp = x + ((size_t)b * L_SEQ + t) * 32;
  float xin[32];
#pragma unroll
  for (int j = 0; j < 8; ++j) {
    float4 v = ((const float4*)xp)[j];
    xin[4*j+0] = v.x; xin[4*j+1] = v.y; xin[4*j+2] = v.z; xin[4*j+3] = v.w;
  }
  float* hp = h + ((size_t)b * TBUF + (t - TOFF)) * 64;
#pragma unroll 2
  for (int oc = 0; oc < 64; ++oc) {
    float a0 = bias[oc], a1 = 0.f;
#pragma unroll
    for (int k = 0; k < 32; k += 2) {
      a0 += w[oc * 32 + k]     * xin[k];
      a1 += w[oc * 32 + k + 1] * xin[k + 1];
    }
    hp[oc] = a0 + a1;
  }
}

// ---------------------------------------------------------------------------
// fused WaveNet layer. One lane = one (b, t) position.
// normal: h_out[t] = h[t] + res_b + res_w @ z(t), z = tanh(f)*sigmoid(g)
// special (t == L virtual position): skip_last[b] += skip_b + skip_w @ z(L)
//   where z(L) uses only tap0 at h[L-d] (tap1 hits zero padding)
// ---------------------------------------------------------------------------
template <bool SPECIAL>
__device__ inline void layer_body(
    int b, int t, int d,
    const float* __restrict__ hin, float* __restrict__ hout,
    const float* __restrict__ pk, const float* __restrict__ wT,
    const float* __restrict__ fb, const float* __restrict__ gb,
    const float* __restrict__ ob, float* __restrict__ skip_last)
{
  float hprev[64], hcur[64], acc[64];
  const float* hpv = hin + ((size_t)b * TBUF + (t - d - TOFF)) * 64;
#pragma unroll
  for (int j = 0; j < 16; ++j) {
    float4 v = ((const float4*)hpv)[j];
    hprev[4*j+0] = v.x; hprev[4*j+1] = v.y; hprev[4*j+2] = v.z; hprev[4*j+3] = v.w;
  }
  if (SPECIAL) {
#pragma unroll
    for (int k = 0; k < 64; ++k) { hcur[k] = 0.f; acc[k] = ob[k]; }
  } else {
    const float* hcv = hin + ((size_t)b * TBUF + (t - TOFF)) * 64;
#pragma unroll
    for (int j = 0; j < 16; ++j) {
      float4 v = ((const float4*)hcv)[j];
      hcur[4*j+0] = v.x; hcur[4*j+1] = v.y; hcur[4*j+2] = v.z; hcur[4*j+3] = v.w;
    }
#pragma unroll
    for (int k = 0; k < 64; ++k) acc[k] = hcur[k] + ob[k];
  }

#pragma unroll 2
  for (int oc = 0; oc < 64; ++oc) {
    const float* w = pk + oc * 256;
    float f0 = fb[oc], f1 = 0.f, g0 = gb[oc], g1 = 0.f;
#pragma unroll
    for (int k = 0; k < 64; k += 2) {
      f0 += w[k]           * hprev[k];
      f1 += w[k + 1]       * hprev[k + 1];
      g0 += w[128 + k]     * hprev[k];
      g1 += w[128 + k + 1] * hprev[k + 1];
    }
    if (!SPECIAL) {
#pragma unroll
      for (int k = 0; k < 64; k += 2) {
        f0 += w[64 + k]      * hcur[k];
        f1 += w[64 + k + 1]  * hcur[k + 1];
        g0 += w[192 + k]     * hcur[k];
        g1 += w[192 + k + 1] * hcur[k + 1];
      }
    }
    float z = fast_tanh(f0 + f1) * fast_sigmoid(g0 + g1);
    const float* rw = wT + oc * 64;
#pragma unroll
    for (int k = 0; k < 64; ++k) acc[k] += rw[k] * z;
  }

  if (SPECIAL) {
    // one lane per (b, layer): plain RMW is race-free (launches serialized)
    for (int k = 0; k < 64; ++k) skip_last[b * 64 + k] += acc[k];
  } else {
    float* hop = hout + ((size_t)b * TBUF + (t - TOFF)) * 64;
#pragma unroll
    for (int j = 0; j < 16; ++j) {
      ((float4*)hop)[j] = make_float4(acc[4*j+0], acc[4*j+1], acc[4*j+2], acc[4*j+3]);
    }
  }
}

__global__ __launch_bounds__(256, 2) void layer_kernel(
    const float* __restrict__ hin, float* __restrict__ hout,
    const float* __restrict__ pk, const float* __restrict__ resT,
    const float* __restrict__ skipT,
    const float* __restrict__ fb, const float* __restrict__ gb,
    const float* __restrict__ rb, const float* __restrict__ sb,
    float* __restrict__ skip_last, int d, int tstart)
{
  int b = blockIdx.y;
  if (blockIdx.x == gridDim.x - 1) {
    if (threadIdx.x == 0)
      layer_body<true>(b, L_SEQ, d, hin, nullptr, pk, skipT, fb, gb, sb, skip_last);
    return;
  }
  int t = tstart + blockIdx.x * 256 + threadIdx.x;
  if (t >= L_SEQ) return;
  layer_body<false>(b, t, d, hin, hout, pk, resT, fb, gb, rb, skip_last);
}

// ---------------------------------------------------------------------------
// epilogue: relu -> end1 (64->128) -> relu -> mean/lv heads -> vol
// out = [mean(32) | log_var(32) | vol(32)]
// ---------------------------------------------------------------------------
__global__ __launch_bounds__(64) void final_kernel(
    const float* __restrict__ skip_last,
    const float* __restrict__ e1w, const float* __restrict__ e1b,
    const float* __restrict__ mw,  const float* __restrict__ mb,
    const float* __restrict__ lw,  const float* __restrict__ lb,
    float* __restrict__ out)
{
  int b = threadIdx.x;
  if (b >= BATCH) return;
  float y1[64];
#pragma unroll
  for (int c = 0; c < 64; ++c) y1[c] = fmaxf(skip_last[b * 64 + c], 0.f);
  float mean = mb[0], lv = lb[0];
#pragma unroll 2
  for (int e = 0; e < 128; ++e) {
    float a0 = e1b[e], a1 = 0.f;
#pragma unroll
    for (int c = 0; c < 64; c += 2) {
      a0 += e1w[e * 64 + c]     * y1[c];
      a1 += e1w[e * 64 + c + 1] * y1[c + 1];
    }
    float a = fmaxf(a0 + a1, 0.f);
    mean += mw[e] * a;
    lv   += lw[e] * a;
  }
  out[b]      = mean;
  out[32 + b] = lv;
  out[64 + b] = expf(0.5f * lv);
}

// ---------------------------------------------------------------------------
extern "C" void kernel_launch(void* const* d_in, const int* in_sizes, int n_in,
                              void* d_out, int out_size, void* d_ws, size_t ws_size,
                              hipStream_t stream)
{
  const float* x       = (const float*)d_in[0];
  const float* input_w = (const float*)d_in[1];
  const float* input_b = (const float*)d_in[2];
  const float* dil_w   = (const float*)d_in[3];
  const float* dil_b   = (const float*)d_in[4];
  const float* gate_w  = (const float*)d_in[5];
  const float* gate_b  = (const float*)d_in[6];
  const float* skip_w  = (const float*)d_in[7];
  const float* skip_b  = (const float*)d_in[8];
  const float* res_w   = (const float*)d_in[9];
  const float* res_b   = (const float*)d_in[10];
  const float* e1w     = (const float*)d_in[11];
  const float* e1b     = (const float*)d_in[12];
  const float* mw      = (const float*)d_in[13];
  const float* mb      = (const float*)d_in[14];
  const float* lw      = (const float*)d_in[15];
  const float* lb      = (const float*)d_in[16];

  float* ws        = (float*)d_ws;
  float* hA        = ws;
  float* hB        = hA + HSZ;
  float* skip_last = hB + HSZ;
  float* pk        = skip_last + BATCH * 64;
  float* resT      = pk + (size_t)NLAYERS * 64 * 256;
  float* skipT     = resT + (size_t)NLAYERS * 64 * 64;

  int dil[NLAYERS];
  int R[NLAYERS + 1];
  for (int blk = 0; blk < 3; ++blk)
    for (int l = 0; l < 10; ++l) dil[blk * 10 + l] = 1 << l;
  R[NLAYERS] = L_SEQ;
  for (int i = NLAYERS - 1; i >= 0; --i) R[i] = R[i + 1] - dil[i];
  // R[0] == 1027: h0 needed only for t in [1027, 4096)

  {
    int total = NLAYERS * 64 * 256;
    prep_kernel<<<(total + 255) / 256, 256, 0, stream>>>(
        dil_w, gate_w, res_w, skip_w, pk, resT, skipT, skip_last);
  }
  {
    int nt = L_SEQ - R[0];  // 3069
    dim3 g((nt + 255) / 256, BATCH);
    input_conv_kernel<<<g, 256, 0, stream>>>(x, input_w, input_b, hA);
  }

  float* hin  = hA;
  float* hout = hB;
  for (int i = 0; i < NLAYERS; ++i) {
    int nt = L_SEQ - R[i + 1];          // #normal output positions (0 for last layer)
    dim3 g((nt + 255) / 256 + 1, BATCH);  // +1 tail block = skip position t=L
    layer_kernel<<<g, 256, 0, stream>>>(
        hin, hout,
        pk   + (size_t)i * 64 * 256,
        resT + (size_t)i * 64 * 64,
        skipT+ (size_t)i * 64 * 64,
        dil_b + i * 64, gate_b + i * 64, res_b + i * 64, skip_b + i * 64,
        skip_last, dil[i], R[i + 1]);
    float* tmp = hin; hin = hout; hout = tmp;
  }

  final_kernel<<<1, 64, 0, stream>>>(skip_last, e1w, e1b, mw, mb, lw, lb,
                                     (float*)d_out);
}

// Round 2
// 829.171 us; speedup vs baseline: 7.0985x; 7.0985x over previous
//
#include <hip/hip_runtime.h>
#include <hip/hip_bf16.h>
#include <cstddef>

#define L_SEQ   4096
#define BATCH   32
#define TOFF    1024
#define TBUF    3072
#define NLAYERS 30

typedef __attribute__((ext_vector_type(8))) short short8v;
typedef __attribute__((ext_vector_type(4))) float f32x4;

static const size_t HSZ = (size_t)BATCH * TBUF * 64;

// LDS byte offsets (dynamic smem, 64 KB total)
#define LDS_A  0        // 64 rows x 128 k bf16, stride 256B  (16 KB)
#define LDS_B  16384    // 128 rows x 128 k bf16, stride 256B (32 KB)
#define LDS_Z  49152    // 64 rows x 64 k bf16, stride 128B   (8 KB)
#define LDS_W  57344    // 64 rows x 64 k bf16, stride 128B   (8 KB)

__device__ inline float fast_sigmoid(float x) {
  x = fminf(fmaxf(x, -30.f), 30.f);
  return __builtin_amdgcn_rcpf(1.f + __expf(-x));
}
__device__ inline float fast_tanh(float x) {
  x = fminf(fmaxf(x, -15.f), 15.f);
  float e = __expf(-2.f * x);
  return (1.f - e) * __builtin_amdgcn_rcpf(1.f + e);
}
__device__ inline unsigned short f2bf(float f) {  // RNE fp32 -> bf16
  unsigned u = __float_as_uint(f);
  unsigned r = u + 0x7FFF + ((u >> 16) & 1);
  return (unsigned short)(r >> 16);
}

// swizzled LDS fragment read: 8 contiguous bf16 at (row, k), XOR bank swizzle
__device__ inline short8v lds_frag(const char* smem, int base, int row, int kk,
                                   int rowstride) {
  int byte = base + row * rowstride + kk * 2;
  byte ^= (row & 7) << 4;
  return *(const short8v*)(smem + byte);
}

// ---------------------------------------------------------------------------
// prep: bf16-pack W1 = [30][n=128 (f|g)][k=128 (hprev|hcur)], WrT = res_w,
// zero skip_last
// ---------------------------------------------------------------------------
__global__ __launch_bounds__(256) void prep_kernel(
    const float* __restrict__ dil_w, const float* __restrict__ gate_w,
    const float* __restrict__ res_w,
    unsigned short* __restrict__ W1bf, unsigned short* __restrict__ Wrbf,
    float* __restrict__ skip_last)
{
  int idx = blockIdx.x * 256 + threadIdx.x;
  if (idx < NLAYERS * 128 * 128) {
    int l = idx >> 14, r = idx & 16383, n = r >> 7, k = r & 127;
    const float* src = (n < 64) ? dil_w : gate_w;
    int oc = n & 63;
    float v = src[(((size_t)l * 64 + oc) * 64 + (k & 63)) * 2 + (k >> 6)];
    W1bf[idx] = f2bf(v);
  }
  if (idx < NLAYERS * 64 * 64) Wrbf[idx] = f2bf(res_w[idx]);  // same flat layout
  if (idx < BATCH * 64) skip_last[idx] = 0.f;
}

// ---------------------------------------------------------------------------
// input 1x1 conv (fp32): h0[b][t][c], t in [1027, 4096)
// ---------------------------------------------------------------------------
__global__ __launch_bounds__(256) void input_conv_kernel(
    const float* __restrict__ x, const float* __restrict__ w,
    const float* __restrict__ bias, float* __restrict__ h)
{
  int b = blockIdx.y;
  int t = 1027 + blockIdx.x * 256 + threadIdx.x;
  if (t >= L_SEQ) return;
  const float* xp = x + ((size_t)b * L_SEQ + t) * 32;
  float xin[32];
#pragma unroll
  for (int j = 0; j < 8; ++j) {
    float4 v = ((const float4*)xp)[j];
    xin[4*j+0] = v.x; xin[4*j+1] = v.y; xin[4*j+2] = v.z; xin[4*j+3] = v.w;
  }
  float* hp = h + ((size_t)b * TBUF + (t - TOFF)) * 64;
#pragma unroll 2
  for (int oc = 0; oc < 64; ++oc) {
    float a0 = bias[oc], a1 = 0.f;
#pragma unroll
    for (int k = 0; k < 32; k += 2) {
      a0 += w[oc * 32 + k]     * xin[k];
      a1 += w[oc * 32 + k + 1] * xin[k + 1];
    }
    hp[oc] = a0 + a1;
  }
}

// ---------------------------------------------------------------------------
// fused MFMA layer: per block, 64 positions x one batch.
//   GEMM1: [64 x K=128(hprev|hcur)] @ W1[128x128] -> f|g ; z = tanh(f)*sig(g)
//   GEMM2: [64 x 64(z)] @ Wr[64x64] -> r ; h_out = hcur + r (fp32 residual)
// tail block (blockIdx.x == gridDim.x-1): skip tap at virtual t = L (VALU)
// ---------------------------------------------------------------------------
__global__ __launch_bounds__(256, 2) void layer_kernel(
    const float* __restrict__ hin, float* __restrict__ hout,
    const unsigned short* __restrict__ W1bf, const unsigned short* __restrict__ Wrbf,
    const float* __restrict__ dil_w, const float* __restrict__ gate_w,
    const float* __restrict__ skip_w,
    const float* __restrict__ dil_b, const float* __restrict__ gate_b,
    const float* __restrict__ res_b, const float* __restrict__ skip_b,
    float* __restrict__ skip_last, int layer, int d, int tstart)
{
  extern __shared__ char smem[];
  const int b = blockIdx.y;
  const int tid = threadIdx.x;

  if (blockIdx.x == gridDim.x - 1) {
    // ---- skip tail at t = L: z uses only tap0 at h[L-d] ----
    float* hp = (float*)smem;
    float* zl = hp + 64;
    if (tid < 64)
      hp[tid] = hin[((size_t)b * TBUF + (L_SEQ - d - TOFF)) * 64 + tid];
    __syncthreads();
    if (tid < 64) {
      int dc = tid;
      float f = dil_b[layer * 64 + dc], gg = gate_b[layer * 64 + dc];
      const float* wd = dil_w  + (size_t)(layer * 64 + dc) * 128;
      const float* wg = gate_w + (size_t)(layer * 64 + dc) * 128;
      for (int ic = 0; ic < 64; ++ic) {
        f  += wd[ic * 2] * hp[ic];
        gg += wg[ic * 2] * hp[ic];
      }
      zl[dc] = fast_tanh(f) * fast_sigmoid(gg);
    }
    __syncthreads();
    if (tid < 64) {
      int co = tid;
      float s = skip_b[layer * 64 + co];
      const float* wsk = skip_w + (size_t)(layer * 64 + co) * 64;
      for (int dc = 0; dc < 64; ++dc) s += wsk[dc] * zl[dc];
      skip_last[b * 64 + co] += s;   // race-free: launches serialize layers
    }
    return;
  }

  const int t0 = tstart + blockIdx.x * 64;

  // ---- stage A: h fp32 -> bf16 LDS [64][128], swizzled ----
  {
    int row = tid >> 2, part = tid & 3;
    int t = t0 + row; if (t >= L_SEQ) t = L_SEQ - 1;   // clamp, discard at write
    int tsrc = (part < 2) ? (t - d) : t;
    const float* src = hin + ((size_t)b * TBUF + (tsrc - TOFF)) * 64 + (part & 1) * 32;
    float v[32];
#pragma unroll
    for (int q = 0; q < 8; ++q) {
      float4 f4 = ((const float4*)src)[q];
      v[4*q] = f4.x; v[4*q+1] = f4.y; v[4*q+2] = f4.z; v[4*q+3] = f4.w;
    }
#pragma unroll
    for (int c = 0; c < 4; ++c) {
      short8v pk;
#pragma unroll
      for (int e = 0; e < 8; ++e) pk[e] = (short)f2bf(v[c * 8 + e]);
      int byte = row * 256 + part * 64 + c * 16;
      byte ^= (row & 7) << 4;
      *(short8v*)(smem + LDS_A + byte) = pk;
    }
  }
  // ---- stage B: W1bf -> LDS [128][128], swizzled ----
  {
    int n = tid >> 1, half = tid & 1;
    const short8v* src =
        (const short8v*)(W1bf + (size_t)layer * 128 * 128 + n * 128 + half * 64);
#pragma unroll
    for (int c = 0; c < 8; ++c) {
      short8v pk = src[c];
      int byte = n * 256 + half * 128 + c * 16;
      byte ^= (n & 7) << 4;
      *(short8v*)(smem + LDS_B + byte) = pk;
    }
  }
  // ---- stage Wr: Wrbf -> LDS [64][64], swizzled ----
  {
    int co = tid >> 2, q = tid & 3;
    const short8v* src =
        (const short8v*)(Wrbf + (size_t)layer * 64 * 64 + co * 64 + q * 16);
#pragma unroll
    for (int c = 0; c < 2; ++c) {
      short8v pk = src[c];
      int byte = co * 128 + q * 32 + c * 16;
      byte ^= (co & 7) << 4;
      *(short8v*)(smem + LDS_W + byte) = pk;
    }
  }
  __syncthreads();

  const int lane = tid & 63;
  const int wid  = tid >> 6;
  const int r0   = wid * 16;        // wave's 16 position-rows
  const int lcol = lane & 15;
  const int lg   = lane >> 4;       // lane group (k-slot group)

  // ---- GEMM1: C[pos][n=f|g], bias pre-seeded ----
  f32x4 cf[8];
#pragma unroll
  for (int j = 0; j < 8; ++j) {
    int n = j * 16 + lcol;
    float bias = (n < 64) ? dil_b[layer * 64 + n] : gate_b[layer * 64 + n - 64];
    cf[j] = (f32x4){bias, bias, bias, bias};
  }
#pragma unroll
  for (int s = 0; s < 4; ++s) {
    short8v a = lds_frag(smem, LDS_A, r0 + lcol, s * 32 + lg * 8, 256);
#pragma unroll
    for (int j = 0; j < 8; ++j) {
      short8v bb = lds_frag(smem, LDS_B, j * 16 + lcol, s * 32 + lg * 8, 256);
      cf[j] = __builtin_amdgcn_mfma_f32_16x16x32_bf16(a, bb, cf[j], 0, 0, 0);
    }
  }

  // ---- activation, z -> LDS bf16 (own-wave rows: no barrier needed) ----
#pragma unroll
  for (int j = 0; j < 4; ++j) {
#pragma unroll
    for (int r = 0; r < 4; ++r) {
      float z = fast_tanh(cf[j][r]) * fast_sigmoid(cf[j + 4][r]);
      int row = r0 + lg * 4 + r;          // C layout: row=(lane>>4)*4+reg
      int col = j * 16 + lcol;            //           col=lane&15
      int byte = row * 128 + col * 2;
      byte ^= (row & 7) << 4;
      *(unsigned short*)(smem + LDS_Z + byte) = f2bf(z);
    }
  }

  // ---- GEMM2: r[pos][co] = z @ Wr^T, bias pre-seeded ----
  f32x4 c2[4];
#pragma unroll
  for (int j = 0; j < 4; ++j) {
    float bias = res_b[layer * 64 + j * 16 + lcol];
    c2[j] = (f32x4){bias, bias, bias, bias};
  }
#pragma unroll
  for (int s = 0; s < 2; ++s) {
    short8v a2 = lds_frag(smem, LDS_Z, r0 + lcol, s * 32 + lg * 8, 128);
#pragma unroll
    for (int j = 0; j < 4; ++j) {
      short8v b2 = lds_frag(smem, LDS_W, j * 16 + lcol, s * 32 + lg * 8, 128);
      c2[j] = __builtin_amdgcn_mfma_f32_16x16x32_bf16(a2, b2, c2[j], 0, 0, 0);
    }
  }

  // ---- epilogue: fp32 residual add ----
#pragma unroll
  for (int j = 0; j < 4; ++j) {
    int col = j * 16 + lcol;
#pragma unroll
    for (int r = 0; r < 4; ++r) {
      int row = r0 + lg * 4 + r;
      int t = t0 + row;
      if (t < L_SEQ) {
        size_t idx = ((size_t)b * TBUF + t - TOFF) * 64 + col;
        hout[idx] = hin[idx] + c2[j][r];
      }
    }
  }
}

// ---------------------------------------------------------------------------
// epilogue: relu -> end1 (64->128) -> relu -> mean/lv heads -> vol
// ---------------------------------------------------------------------------
__global__ __launch_bounds__(64) void final_kernel(
    const float* __restrict__ skip_last,
    const float* __restrict__ e1w, const float* __restrict__ e1b,
    const float* __restrict__ mw,  const float* __restrict__ mb,
    const float* __restrict__ lw,  const float* __restrict__ lb,
    float* __restrict__ out)
{
  int b = threadIdx.x;
  if (b >= BATCH) return;
  float y1[64];
#pragma unroll
  for (int c = 0; c < 64; ++c) y1[c] = fmaxf(skip_last[b * 64 + c], 0.f);
  float mean = mb[0], lv = lb[0];
#pragma unroll 2
  for (int e = 0; e < 128; ++e) {
    float a0 = e1b[e], a1 = 0.f;
#pragma unroll
    for (int c = 0; c < 64; c += 2) {
      a0 += e1w[e * 64 + c]     * y1[c];
      a1 += e1w[e * 64 + c + 1] * y1[c + 1];
    }
    float a = fmaxf(a0 + a1, 0.f);
    mean += mw[e] * a;
    lv   += lw[e] * a;
  }
  out[b]      = mean;
  out[32 + b] = lv;
  out[64 + b] = expf(0.5f * lv);
}

// ---------------------------------------------------------------------------
extern "C" void kernel_launch(void* const* d_in, const int* in_sizes, int n_in,
                              void* d_out, int out_size, void* d_ws, size_t ws_size,
                              hipStream_t stream)
{
  const float* x       = (const float*)d_in[0];
  const float* input_w = (const float*)d_in[1];
  const float* input_b = (const float*)d_in[2];
  const float* dil_w   = (const float*)d_in[3];
  const float* dil_b   = (const float*)d_in[4];
  const float* gate_w  = (const float*)d_in[5];
  const float* gate_b  = (const float*)d_in[6];
  const float* skip_w  = (const float*)d_in[7];
  const float* skip_b  = (const float*)d_in[8];
  const float* res_w   = (const float*)d_in[9];
  const float* res_b   = (const float*)d_in[10];
  const float* e1w     = (const float*)d_in[11];
  const float* e1b     = (const float*)d_in[12];
  const float* mw      = (const float*)d_in[13];
  const float* mb      = (const float*)d_in[14];
  const float* lw      = (const float*)d_in[15];
  const float* lb      = (const float*)d_in[16];

  float* ws        = (float*)d_ws;
  float* hA        = ws;
  float* hB        = hA + HSZ;
  float* skip_last = hB + HSZ;
  unsigned short* W1bf = (unsigned short*)(skip_last + BATCH * 64);
  unsigned short* Wrbf = W1bf + (size_t)NLAYERS * 128 * 128;

  int dil[NLAYERS];
  int R[NLAYERS + 1];
  for (int blk = 0; blk < 3; ++blk)
    for (int l = 0; l < 10; ++l) dil[blk * 10 + l] = 1 << l;
  R[NLAYERS] = L_SEQ;
  for (int i = NLAYERS - 1; i >= 0; --i) R[i] = R[i + 1] - dil[i];
  // R[0] == 1027

  prep_kernel<<<(NLAYERS * 128 * 128 + 255) / 256, 256, 0, stream>>>(
      dil_w, gate_w, res_w, W1bf, Wrbf, skip_last);

  {
    int nt = L_SEQ - R[0];  // 3069
    dim3 g((nt + 255) / 256, BATCH);
    input_conv_kernel<<<g, 256, 0, stream>>>(x, input_w, input_b, hA);
  }

  float* hin  = hA;
  float* hout = hB;
  for (int i = 0; i < NLAYERS; ++i) {
    int nt = L_SEQ - R[i + 1];            // normal positions (0 for last layer)
    int nblk = (nt + 63) / 64;
    dim3 g(nblk + 1, BATCH);              // +1 tail block for skip @ t=L
    layer_kernel<<<g, 256, 65536, stream>>>(
        hin, hout, W1bf, Wrbf,
        dil_w, gate_w, skip_w,
        dil_b, gate_b, res_b, skip_b,
        skip_last, i, dil[i], R[i + 1]);
    float* tmp = hin; hin = hout; hout = tmp;
  }

  final_kernel<<<1, 64, 0, stream>>>(skip_last, e1w, e1b, mw, mb, lw, lb,
                                     (float*)d_out);
}